// Round 1
// baseline (674.012 us; speedup 1.0000x reference)
//
#include <hip/hip_runtime.h>

typedef unsigned short u16;
typedef __attribute__((ext_vector_type(8))) short bf16x8;
typedef __attribute__((ext_vector_type(4))) float f32x4;

#define L2E 1.44269504088896340736f

__device__ __forceinline__ u16 f2bf(float f) {
  unsigned u = __float_as_uint(f);
  u += 0x7FFF + ((u >> 16) & 1u);
  return (u16)(u >> 16);
}

__device__ __forceinline__ void gload_lds16(const u16* g, u16* lds) {
  __builtin_amdgcn_global_load_lds(
      (const __attribute__((address_space(1))) void*)g,
      (__attribute__((address_space(3))) void*)lds, 16, 0, 0);
}

// ---------------- convert x (fp32 -> bf16), 4 elems/thread ----------------
__global__ __launch_bounds__(256) void k_cvt(const float* __restrict__ in,
                                             u16* __restrict__ out) {
  const int i = (blockIdx.x * 256 + threadIdx.x) * 4;
  float4 a = *(const float4*)(in + i);
  ushort4 o;
  o.x = f2bf(a.x); o.y = f2bf(a.y); o.z = f2bf(a.z); o.w = f2bf(a.w);
  *(ushort4*)(out + i) = o;
}

// ------------- transpose 1024x1024 fp32 W[k][n] -> bf16 Wt[n][k] -----------
__global__ __launch_bounds__(256) void k_tw(
    const float* __restrict__ w0, const float* __restrict__ w1,
    const float* __restrict__ w2, const float* __restrict__ w3,
    u16* __restrict__ o0, u16* __restrict__ o1,
    u16* __restrict__ o2, u16* __restrict__ o3) {
  __shared__ float t[64][65];
  const float* W = blockIdx.z == 0 ? w0 : blockIdx.z == 1 ? w1 : blockIdx.z == 2 ? w2 : w3;
  u16* O = blockIdx.z == 0 ? o0 : blockIdx.z == 1 ? o1 : blockIdx.z == 2 ? o2 : o3;
  const int nb = blockIdx.x * 64, kb = blockIdx.y * 64;
  const int lx = threadIdx.x & 63, ly = threadIdx.x >> 6;
  for (int r = ly; r < 64; r += 4)
    t[r][lx] = W[(size_t)(kb + r) * 1024 + nb + lx];
  __syncthreads();
  for (int r = ly; r < 64; r += 4)
    O[(size_t)(nb + r) * 1024 + kb + lx] = f2bf(t[lx][r]);
}

// ---------------- 128x128 bf16 GEMM core (m97 structure) -------------------
// A: [M][1024] row-major bf16, Bt: [N][1024] row-major bf16 (= B^T).
// 256 threads = 4 waves in 2x2, each wave 64x64 (4x4 frags of 16x16x32).
__device__ __forceinline__ void gemm_core(const u16* __restrict__ Ag,
                                          const u16* __restrict__ Bg,
                                          f32x4 acc[4][4]) {
  __shared__ u16 As[4096], Bs[4096];
  const int tid = threadIdx.x;
  const int lane = tid & 63, wv = tid >> 6;
  const size_t row0 = (size_t)blockIdx.y * 128;
  const size_t col0 = (size_t)blockIdx.x * 128;
  const int rA0 = wv * 32 + (lane >> 2);
  const int rA1 = rA0 + 16;
  const int kk = (lane & 3) * 8;
  const int wr = (wv >> 1) * 64, wc = (wv & 1) * 64;
  const int fr = lane & 15, fk = (lane >> 4) * 8;
#pragma unroll
  for (int m = 0; m < 4; m++)
#pragma unroll
    for (int n = 0; n < 4; n++)
      acc[m][n] = {0.f, 0.f, 0.f, 0.f};

  for (int kt = 0; kt < 32; kt++) {
    const int k0 = kt * 32;
    gload_lds16(Ag + (row0 + rA0) * 1024 + k0 + kk, &As[(wv * 2 + 0) * 512]);
    gload_lds16(Ag + (row0 + rA1) * 1024 + k0 + kk, &As[(wv * 2 + 1) * 512]);
    gload_lds16(Bg + (col0 + rA0) * 1024 + k0 + kk, &Bs[(wv * 2 + 0) * 512]);
    gload_lds16(Bg + (col0 + rA1) * 1024 + k0 + kk, &Bs[(wv * 2 + 1) * 512]);
    __syncthreads();
    bf16x8 af[4], bfr[4];
#pragma unroll
    for (int m = 0; m < 4; m++)
      af[m] = *(const bf16x8*)&As[(wr + m * 16 + fr) * 32 + fk];
#pragma unroll
    for (int n = 0; n < 4; n++)
      bfr[n] = *(const bf16x8*)&Bs[(wc + n * 16 + fr) * 32 + fk];
#pragma unroll
    for (int m = 0; m < 4; m++)
#pragma unroll
      for (int n = 0; n < 4; n++)
        acc[m][n] = __builtin_amdgcn_mfma_f32_16x16x32_bf16(af[m], bfr[n], acc[m][n], 0, 0, 0);
    __syncthreads();
  }
}

// -------- fused projection GEMM: z=0 -> q (scaled), z=1 -> k, z=2 -> vT ----
__global__ __launch_bounds__(256) void k_proj(
    const u16* __restrict__ xb, const u16* __restrict__ wqT,
    const u16* __restrict__ wkT, const u16* __restrict__ wvT,
    u16* __restrict__ q, u16* __restrict__ k, u16* __restrict__ v) {
  f32x4 acc[4][4];
  const int z = blockIdx.z;
  const u16* Bg = z == 0 ? wqT : z == 1 ? wkT : wvT;
  gemm_core(xb, Bg, acc);
  const int lane = threadIdx.x & 63, wv = threadIdx.x >> 6;
  const int wr = (wv >> 1) * 64, wc = (wv & 1) * 64;
  const int rb = blockIdx.y * 128 + wr + ((lane >> 4) * 4);
  const int cb = blockIdx.x * 128 + wc + (lane & 15);
#pragma unroll
  for (int m = 0; m < 4; m++) {
#pragma unroll
    for (int n = 0; n < 4; n++) {
      const int C = cb + n * 16;
      const int h = C >> 6, d = C & 63;
      if (z == 2) {
        const int R = rb + m * 16;           // 4-aligned
        const int b = R >> 11, nn = R & 2047;
        ushort4 o;
        o.x = f2bf(acc[m][n][0]); o.y = f2bf(acc[m][n][1]);
        o.z = f2bf(acc[m][n][2]); o.w = f2bf(acc[m][n][3]);
        *(ushort4*)&v[(size_t)((b * 16 + h) * 64 + d) * 2048 + nn] = o;
      } else {
        u16* dst = (z == 0) ? q : k;
        const float s = (z == 0) ? 0.03125f : 1.0f;
#pragma unroll
        for (int i = 0; i < 4; i++) {
          const int R = rb + m * 16 + i;
          const int b = R >> 11, nn = R & 2047;
          dst[(size_t)((b * 16 + h) * 2048 + nn) * 64 + d] = f2bf(acc[m][n][i] * s);
        }
      }
    }
  }
}

// ---------------- output GEMM: att(bf16) @ WoT -> fp32 out -----------------
__global__ __launch_bounds__(256) void k_out(const u16* __restrict__ att,
                                             const u16* __restrict__ woT,
                                             float* __restrict__ out) {
  f32x4 acc[4][4];
  gemm_core(att, woT, acc);
  const int lane = threadIdx.x & 63, wv = threadIdx.x >> 6;
  const int wr = (wv >> 1) * 64, wc = (wv & 1) * 64;
  const int rb = blockIdx.y * 128 + wr + ((lane >> 4) * 4);
  const int cb = blockIdx.x * 128 + wc + (lane & 15);
#pragma unroll
  for (int m = 0; m < 4; m++)
#pragma unroll
    for (int n = 0; n < 4; n++)
#pragma unroll
      for (int i = 0; i < 4; i++)
        out[(size_t)(rb + m * 16 + i) * 1024 + cb + n * 16] = acc[m][n][i];
}

// ---------------- flash attention -----------------------------------------
// grid (32 qtiles, 64 bh), 256 thr = 4 waves; wave owns 16 q-rows.
// q,k: [bh][n][64] bf16 (q pre-scaled 1/32); v: [bh][64][n] bf16.
__global__ __launch_bounds__(256) void k_attn(const u16* __restrict__ q,
                                              const u16* __restrict__ k,
                                              const u16* __restrict__ v,
                                              u16* __restrict__ att) {
  __shared__ u16 P[4][16 * 40];
  const int lane = threadIdx.x & 63, wv = threadIdx.x >> 6;
  const int bh = blockIdx.y;
  const int b = bh >> 4, h = bh & 15;
  const int q0 = blockIdx.x * 64 + wv * 16;
  const size_t base = (size_t)bh * 2048 * 64;

  bf16x8 qf0, qf1;
  {
    const int r = q0 + (lane & 15);
    const int dd = (lane >> 4) * 8;
    qf0 = *(const bf16x8*)&q[base + (size_t)r * 64 + dd];
    qf1 = *(const bf16x8*)&q[base + (size_t)r * 64 + 32 + dd];
  }
  f32x4 acc[4];
#pragma unroll
  for (int n = 0; n < 4; n++) acc[n] = {0.f, 0.f, 0.f, 0.f};
  float mr[4], lr[4];
#pragma unroll
  for (int i = 0; i < 4; i++) { mr[i] = -3.0e38f; lr[i] = 0.f; }

  u16* Pw = &P[wv][0];
  const int prow = (lane >> 4) * 4;
  const int pcol = lane & 15;

  for (int kt = 0; kt < 64; kt++) {
    const int kb = kt * 32;
    f32x4 s[2];
#pragma unroll
    for (int j = 0; j < 2; j++) {
      const size_t koff = base + (size_t)(kb + j * 16 + pcol) * 64 + ((lane >> 4) * 8);
      bf16x8 kf0 = *(const bf16x8*)&k[koff];
      bf16x8 kf1 = *(const bf16x8*)&k[koff + 32];
      f32x4 c = {0.f, 0.f, 0.f, 0.f};
      c = __builtin_amdgcn_mfma_f32_16x16x32_bf16(qf0, kf0, c, 0, 0, 0);
      c = __builtin_amdgcn_mfma_f32_16x16x32_bf16(qf1, kf1, c, 0, 0, 0);
      s[j] = c;
    }
    float tm[4], sc[4], rs[4];
#pragma unroll
    for (int i = 0; i < 4; i++) tm[i] = fmaxf(s[0][i], s[1][i]);
#pragma unroll
    for (int off = 8; off; off >>= 1)
#pragma unroll
      for (int i = 0; i < 4; i++) tm[i] = fmaxf(tm[i], __shfl_xor(tm[i], off, 64));
#pragma unroll
    for (int i = 0; i < 4; i++) {
      const float mn = fmaxf(mr[i], tm[i]);
      sc[i] = exp2f((mr[i] - mn) * L2E);
      mr[i] = mn;
      rs[i] = 0.f;
    }
#pragma unroll
    for (int j = 0; j < 2; j++)
#pragma unroll
      for (int i = 0; i < 4; i++) {
        const float p = exp2f((s[j][i] - mr[i]) * L2E);
        s[j][i] = p;
        rs[i] += p;
      }
#pragma unroll
    for (int off = 8; off; off >>= 1)
#pragma unroll
      for (int i = 0; i < 4; i++) rs[i] += __shfl_xor(rs[i], off, 64);
#pragma unroll
    for (int i = 0; i < 4; i++) lr[i] = lr[i] * sc[i] + rs[i];
#pragma unroll
    for (int n = 0; n < 4; n++)
#pragma unroll
      for (int i = 0; i < 4; i++) acc[n][i] *= sc[i];
    // P (C-layout) -> LDS, re-read as A-fragment
#pragma unroll
    for (int j = 0; j < 2; j++)
#pragma unroll
      for (int i = 0; i < 4; i++)
        Pw[(prow + i) * 40 + j * 16 + pcol] = f2bf(s[j][i]);
    asm volatile("s_waitcnt lgkmcnt(0)" ::: "memory");
    const bf16x8 pa = *(const bf16x8*)&Pw[(lane & 15) * 40 + (lane >> 4) * 8];
#pragma unroll
    for (int n = 0; n < 4; n++) {
      const size_t voff = base + (size_t)(n * 16 + pcol) * 2048 + kb + ((lane >> 4) * 8);
      const bf16x8 vf = *(const bf16x8*)&v[voff];
      acc[n] = __builtin_amdgcn_mfma_f32_16x16x32_bf16(pa, vf, acc[n], 0, 0, 0);
    }
  }
#pragma unroll
  for (int i = 0; i < 4; i++) lr[i] = 1.0f / lr[i];
#pragma unroll
  for (int n = 0; n < 4; n++)
#pragma unroll
    for (int i = 0; i < 4; i++)
      att[(size_t)(b * 2048 + q0 + prow + i) * 1024 + h * 64 + n * 16 + pcol] =
          f2bf(acc[n][i] * lr[i]);
}

extern "C" void kernel_launch(void* const* d_in, const int* in_sizes, int n_in,
                              void* d_out, int out_size, void* d_ws, size_t ws_size,
                              hipStream_t stream) {
  const float* x  = (const float*)d_in[0];
  const float* Wq = (const float*)d_in[1];
  const float* Wk = (const float*)d_in[2];
  const float* Wv = (const float*)d_in[3];
  const float* Wo = (const float*)d_in[4];
  float* out = (float*)d_out;

  char* ws = (char*)d_ws;
  u16* xb  = (u16*)ws; ws += (size_t)8192 * 1024 * 2;
  u16* wqT = (u16*)ws; ws += (size_t)1024 * 1024 * 2;
  u16* wkT = (u16*)ws; ws += (size_t)1024 * 1024 * 2;
  u16* wvT = (u16*)ws; ws += (size_t)1024 * 1024 * 2;
  u16* woT = (u16*)ws; ws += (size_t)1024 * 1024 * 2;
  u16* qb  = (u16*)ws; ws += (size_t)8192 * 1024 * 2;
  u16* kb  = (u16*)ws; ws += (size_t)8192 * 1024 * 2;
  u16* vb  = (u16*)ws; ws += (size_t)8192 * 1024 * 2;
  u16* att = (u16*)ws; ws += (size_t)8192 * 1024 * 2;

  k_cvt<<<dim3(8192), dim3(256), 0, stream>>>(x, xb);
  k_tw<<<dim3(16, 16, 4), dim3(256), 0, stream>>>(Wq, Wk, Wv, Wo, wqT, wkT, wvT, woT);
  k_proj<<<dim3(8, 64, 3), dim3(256), 0, stream>>>(xb, wqT, wkT, wvT, qb, kb, vb);
  k_attn<<<dim3(32, 64), dim3(256), 0, stream>>>(qb, kb, vb, att);
  k_out<<<dim3(8, 64), dim3(256), 0, stream>>>(att, woT, out);
}

// Round 2
// 442.652 us; speedup vs baseline: 1.5227x; 1.5227x over previous
//
#include <hip/hip_runtime.h>

typedef unsigned short u16;
typedef unsigned int u32;
typedef __attribute__((ext_vector_type(8))) short bf16x8;
typedef __attribute__((ext_vector_type(4))) float f32x4;
typedef __attribute__((ext_vector_type(16))) float f32x16;

#define L2E 1.44269504088896340736f

__device__ __forceinline__ u16 f2bf(float f) {
  unsigned u = __float_as_uint(f);
  u += 0x7FFF + ((u >> 16) & 1u);
  return (u16)(u >> 16);
}

__device__ __forceinline__ u32 cvtpk(float lo, float hi) {
  u32 r;
  asm("v_cvt_pk_bf16_f32 %0, %1, %2" : "=v"(r) : "v"(lo), "v"(hi));
  return r;
}

__device__ __forceinline__ void gload_lds16(const u16* g, u16* lds) {
  __builtin_amdgcn_global_load_lds(
      (const __attribute__((address_space(1))) void*)g,
      (__attribute__((address_space(3))) void*)lds, 16, 0, 0);
}

// ---------------- convert x (fp32 -> bf16), 4 elems/thread ----------------
__global__ __launch_bounds__(256) void k_cvt(const float* __restrict__ in,
                                             u16* __restrict__ out) {
  const int i = (blockIdx.x * 256 + threadIdx.x) * 4;
  float4 a = *(const float4*)(in + i);
  ushort4 o;
  o.x = f2bf(a.x); o.y = f2bf(a.y); o.z = f2bf(a.z); o.w = f2bf(a.w);
  *(ushort4*)(out + i) = o;
}

// ------------- transpose 1024x1024 fp32 W[k][n] -> bf16 Wt[n][k] -----------
__global__ __launch_bounds__(256) void k_tw(
    const float* __restrict__ w0, const float* __restrict__ w1,
    const float* __restrict__ w2, const float* __restrict__ w3,
    u16* __restrict__ o0, u16* __restrict__ o1,
    u16* __restrict__ o2, u16* __restrict__ o3) {
  __shared__ float t[64][65];
  const float* W = blockIdx.z == 0 ? w0 : blockIdx.z == 1 ? w1 : blockIdx.z == 2 ? w2 : w3;
  u16* O = blockIdx.z == 0 ? o0 : blockIdx.z == 1 ? o1 : blockIdx.z == 2 ? o2 : o3;
  const int nb = blockIdx.x * 64, kb = blockIdx.y * 64;
  const int lx = threadIdx.x & 63, ly = threadIdx.x >> 6;
  for (int r = ly; r < 64; r += 4)
    t[r][lx] = W[(size_t)(kb + r) * 1024 + nb + lx];
  __syncthreads();
  for (int r = ly; r < 64; r += 4)
    O[(size_t)(nb + r) * 1024 + kb + lx] = f2bf(t[lx][r]);
}

// ---------------- 128x128 bf16 GEMM core (m97 structure) -------------------
__device__ __forceinline__ void gemm_core(const u16* __restrict__ Ag,
                                          const u16* __restrict__ Bg,
                                          f32x4 acc[4][4]) {
  __shared__ u16 As[4096], Bs[4096];
  const int tid = threadIdx.x;
  const int lane = tid & 63, wv = tid >> 6;
  const size_t row0 = (size_t)blockIdx.y * 128;
  const size_t col0 = (size_t)blockIdx.x * 128;
  const int rA0 = wv * 32 + (lane >> 2);
  const int rA1 = rA0 + 16;
  const int kk = (lane & 3) * 8;
  const int wr = (wv >> 1) * 64, wc = (wv & 1) * 64;
  const int fr = lane & 15, fk = (lane >> 4) * 8;
#pragma unroll
  for (int m = 0; m < 4; m++)
#pragma unroll
    for (int n = 0; n < 4; n++)
      acc[m][n] = {0.f, 0.f, 0.f, 0.f};

  for (int kt = 0; kt < 32; kt++) {
    const int k0 = kt * 32;
    gload_lds16(Ag + (row0 + rA0) * 1024 + k0 + kk, &As[(wv * 2 + 0) * 512]);
    gload_lds16(Ag + (row0 + rA1) * 1024 + k0 + kk, &As[(wv * 2 + 1) * 512]);
    gload_lds16(Bg + (col0 + rA0) * 1024 + k0 + kk, &Bs[(wv * 2 + 0) * 512]);
    gload_lds16(Bg + (col0 + rA1) * 1024 + k0 + kk, &Bs[(wv * 2 + 1) * 512]);
    __syncthreads();
    bf16x8 af[4], bfr[4];
#pragma unroll
    for (int m = 0; m < 4; m++)
      af[m] = *(const bf16x8*)&As[(wr + m * 16 + fr) * 32 + fk];
#pragma unroll
    for (int n = 0; n < 4; n++)
      bfr[n] = *(const bf16x8*)&Bs[(wc + n * 16 + fr) * 32 + fk];
#pragma unroll
    for (int m = 0; m < 4; m++)
#pragma unroll
      for (int n = 0; n < 4; n++)
        acc[m][n] = __builtin_amdgcn_mfma_f32_16x16x32_bf16(af[m], bfr[n], acc[m][n], 0, 0, 0);
    __syncthreads();
  }
}

// -------- fused projection GEMM: z=0 -> q (scaled by L2E/32), z=1 -> k, z=2 -> vT
__global__ __launch_bounds__(256) void k_proj(
    const u16* __restrict__ xb, const u16* __restrict__ wqT,
    const u16* __restrict__ wkT, const u16* __restrict__ wvT,
    u16* __restrict__ q, u16* __restrict__ k, u16* __restrict__ v) {
  f32x4 acc[4][4];
  const int z = blockIdx.z;
  const u16* Bg = z == 0 ? wqT : z == 1 ? wkT : wvT;
  gemm_core(xb, Bg, acc);
  const int lane = threadIdx.x & 63, wv = threadIdx.x >> 6;
  const int wr = (wv >> 1) * 64, wc = (wv & 1) * 64;
  const int rb = blockIdx.y * 128 + wr + ((lane >> 4) * 4);
  const int cb = blockIdx.x * 128 + wc + (lane & 15);
#pragma unroll
  for (int m = 0; m < 4; m++) {
#pragma unroll
    for (int n = 0; n < 4; n++) {
      const int C = cb + n * 16;
      const int h = C >> 6, d = C & 63;
      if (z == 2) {
        const int R = rb + m * 16;  // 4-aligned
        const int b = R >> 11, nn = R & 2047;
        ushort4 o;
        o.x = f2bf(acc[m][n][0]); o.y = f2bf(acc[m][n][1]);
        o.z = f2bf(acc[m][n][2]); o.w = f2bf(acc[m][n][3]);
        *(ushort4*)&v[(size_t)((b * 16 + h) * 64 + d) * 2048 + nn] = o;
      } else {
        u16* dst = (z == 0) ? q : k;
        // q pre-scaled by (1/sqrt(1024)) * log2(e) so attention can use exp2 directly
        const float s = (z == 0) ? (0.03125f * L2E) : 1.0f;
#pragma unroll
        for (int i = 0; i < 4; i++) {
          const int R = rb + m * 16 + i;
          const int b = R >> 11, nn = R & 2047;
          dst[(size_t)((b * 16 + h) * 2048 + nn) * 64 + d] = f2bf(acc[m][n][i] * s);
        }
      }
    }
  }
}

// ---------------- output GEMM: att(bf16) @ WoT -> fp32 out -----------------
__global__ __launch_bounds__(256) void k_out(const u16* __restrict__ att,
                                             const u16* __restrict__ woT,
                                             float* __restrict__ out) {
  f32x4 acc[4][4];
  gemm_core(att, woT, acc);
  const int lane = threadIdx.x & 63, wv = threadIdx.x >> 6;
  const int wr = (wv >> 1) * 64, wc = (wv & 1) * 64;
  const int rb = blockIdx.y * 128 + wr + ((lane >> 4) * 4);
  const int cb = blockIdx.x * 128 + wc + (lane & 15);
#pragma unroll
  for (int m = 0; m < 4; m++)
#pragma unroll
    for (int n = 0; n < 4; n++)
#pragma unroll
      for (int i = 0; i < 4; i++)
        out[(size_t)(rb + m * 16 + i) * 1024 + cb + n * 16] = acc[m][n][i];
}

// ---------------- flash attention, 32x32 swapped-operand structure ---------
// grid (16 qtiles, 64 bh), 256 thr = 4 waves; each wave owns 32 q-rows.
// q,k: [bh][n][64] bf16 (q pre-scaled by L2E/32); v: [bh][64][n] bf16.
// QK^T computed swapped: S^T = mfma(K, Q)  -> lane holds S[keys][q=lane&31]
// PV computed swapped:   O^T = mfma(V^T,P) -> lane holds O[d...][q=lane&31]
// => softmax reduction = 31 in-reg ops + one shfl_xor(32); rescale is per-lane.
__global__ __launch_bounds__(256, 2) void k_attn(const u16* __restrict__ q,
                                                 const u16* __restrict__ k,
                                                 const u16* __restrict__ v,
                                                 u16* __restrict__ att) {
  __shared__ u16 OT[4][32 * 68];
  const int lane = threadIdx.x & 63, wv = threadIdx.x >> 6;
  const int lo5 = lane & 31, hi = lane >> 5;
  const int bh = blockIdx.y;
  const int b = bh >> 4, h = bh & 15;
  const int q0w = blockIdx.x * 128 + wv * 32;
  const size_t base = (size_t)bh * 2048 * 64;  // same for q,k and v ([64][2048])

  // Q as B-fragments: qb[db] holds Q[q=lo5][d = db*16 + hi*8 + i]
  bf16x8 qb[4];
  {
    const u16* qp = q + base + (size_t)(q0w + lo5) * 64 + hi * 8;
#pragma unroll
    for (int db = 0; db < 4; db++) qb[db] = *(const bf16x8*)(qp + db * 16);
  }

  f32x16 o0, o1;
#pragma unroll
  for (int i = 0; i < 16; i++) { o0[i] = 0.f; o1[i] = 0.f; }
  float m_run = -3.0e38f, l_run = 0.f;

  const u16* kp = k + base + (size_t)lo5 * 64 + hi * 8;
  const u16* vp = v + base + (size_t)lo5 * 2048 + hi * 8;   // d = lo5 (+32 for o1)

  for (int kt = 0; kt < 32; kt++) {
    const int kb = kt * 64;
    // ---- K fragments: kf[kh*4+db] = K[kb + kh*32 + lo5][db*16 + hi*8 + i]
    bf16x8 kf[8];
#pragma unroll
    for (int kh = 0; kh < 2; kh++)
#pragma unroll
      for (int db = 0; db < 4; db++)
        kf[kh * 4 + db] = *(const bf16x8*)(kp + (size_t)(kb + kh * 32) * 64 + db * 16);

    // ---- S^T = K · Q^T : col = q (lane&31), row = key
    f32x16 s0, s1;
#pragma unroll
    for (int i = 0; i < 16; i++) { s0[i] = 0.f; s1[i] = 0.f; }
#pragma unroll
    for (int db = 0; db < 4; db++) {
      s0 = __builtin_amdgcn_mfma_f32_32x32x16_bf16(kf[db], qb[db], s0, 0, 0, 0);
      s1 = __builtin_amdgcn_mfma_f32_32x32x16_bf16(kf[4 + db], qb[db], s1, 0, 0, 0);
    }

    // ---- online softmax (values already in log2 domain; q pre-scaled by L2E)
    float t[16];
#pragma unroll
    for (int i = 0; i < 16; i++) t[i] = fmaxf(s0[i], s1[i]);
#pragma unroll
    for (int off = 8; off; off >>= 1)
#pragma unroll
      for (int i = 0; i < off; i++) t[i] = fmaxf(t[i], t[i + off]);
    float tmax = fmaxf(t[0], __shfl_xor(t[0], 32, 64));
    const float mnew = fmaxf(m_run, tmax);
    const float sc = exp2f(m_run - mnew);
    m_run = mnew;

    float p0[16], p1[16];
#pragma unroll
    for (int i = 0; i < 16; i++) {
      p0[i] = exp2f(s0[i] - mnew);
      p1[i] = exp2f(s1[i] - mnew);
    }
    float u[16];
#pragma unroll
    for (int i = 0; i < 16; i++) u[i] = p0[i] + p1[i];
#pragma unroll
    for (int off = 8; off; off >>= 1)
#pragma unroll
      for (int i = 0; i < off; i++) u[i] += u[i + off];
    const float rs = u[0] + __shfl_xor(u[0], 32, 64);
    l_run = l_run * sc + rs;
#pragma unroll
    for (int i = 0; i < 16; i++) { o0[i] *= sc; o1[i] *= sc; }

    // ---- pack P -> bf16 B-fragments pa[ks]: P[key = kb+ks*16+hi*8+i][q=lo5]
    bf16x8 pa[4];
#pragma unroll
    for (int kh = 0; kh < 2; kh++) {
      const float* pp = kh ? p1 : p0;
#pragma unroll
      for (int kl = 0; kl < 2; kl++) {
        const int r0 = kl * 8;
        const u32 a0 = cvtpk(pp[r0 + 0], pp[r0 + 1]);
        const u32 a1 = cvtpk(pp[r0 + 2], pp[r0 + 3]);
        const u32 b0 = cvtpk(pp[r0 + 4], pp[r0 + 5]);
        const u32 b1 = cvtpk(pp[r0 + 6], pp[r0 + 7]);
        const u32 a0x = (u32)__shfl_xor((int)a0, 32, 64);
        const u32 a1x = (u32)__shfl_xor((int)a1, 32, 64);
        const u32 b0x = (u32)__shfl_xor((int)b0, 32, 64);
        const u32 b1x = (u32)__shfl_xor((int)b1, 32, 64);
        union { u32 w[4]; bf16x8 v; } U;
        U.w[0] = hi ? b0x : a0;
        U.w[1] = hi ? b1x : a1;
        U.w[2] = hi ? b0 : a0x;
        U.w[3] = hi ? b1 : a1x;
        pa[kh * 2 + kl] = U.v;
      }
    }

    // ---- O^T += V^T · P : rows = d, col = q
#pragma unroll
    for (int ks = 0; ks < 4; ks++) {
      const bf16x8 vf0 = *(const bf16x8*)(vp + kb + ks * 16);
      o0 = __builtin_amdgcn_mfma_f32_32x32x16_bf16(vf0, pa[ks], o0, 0, 0, 0);
    }
#pragma unroll
    for (int ks = 0; ks < 4; ks++) {
      const bf16x8 vf1 = *(const bf16x8*)(vp + (size_t)32 * 2048 + kb + ks * 16);
      o1 = __builtin_amdgcn_mfma_f32_32x32x16_bf16(vf1, pa[ks], o1, 0, 0, 0);
    }
  }

  // ---- epilogue: normalize, transpose via per-wave LDS, coalesced store
  const float linv = 1.0f / l_run;
  u16* W = &OT[wv][0];
#pragma unroll
  for (int r = 0; r < 16; r++) {
    const int dd = (r & 3) + 8 * (r >> 2) + 4 * hi;
    W[lo5 * 68 + dd] = f2bf(o0[r] * linv);
    W[lo5 * 68 + 32 + dd] = f2bf(o1[r] * linv);
  }
  // same-wave LDS readback (compiler inserts lgkmcnt waits; no barrier needed)
  const int q_loc = lane >> 1, dh = (lane & 1) * 32;
  u16* dst = att + (size_t)(b * 2048 + q0w + q_loc) * 1024 + h * 64 + dh;
#pragma unroll
  for (int c = 0; c < 2; c++) {
    bf16x8 val = *(const bf16x8*)&W[q_loc * 68 + dh + c * 8];
    *(bf16x8*)(dst + c * 8) = val;
  }
#pragma unroll
  for (int c = 2; c < 4; c++) {
    bf16x8 val = *(const bf16x8*)&W[q_loc * 68 + dh + c * 8];
    *(bf16x8*)(dst + c * 8) = val;
  }
}

extern "C" void kernel_launch(void* const* d_in, const int* in_sizes, int n_in,
                              void* d_out, int out_size, void* d_ws, size_t ws_size,
                              hipStream_t stream) {
  const float* x  = (const float*)d_in[0];
  const float* Wq = (const float*)d_in[1];
  const float* Wk = (const float*)d_in[2];
  const float* Wv = (const float*)d_in[3];
  const float* Wo = (const float*)d_in[4];
  float* out = (float*)d_out;

  char* ws = (char*)d_ws;
  u16* xb  = (u16*)ws; ws += (size_t)8192 * 1024 * 2;
  u16* wqT = (u16*)ws; ws += (size_t)1024 * 1024 * 2;
  u16* wkT = (u16*)ws; ws += (size_t)1024 * 1024 * 2;
  u16* wvT = (u16*)ws; ws += (size_t)1024 * 1024 * 2;
  u16* woT = (u16*)ws; ws += (size_t)1024 * 1024 * 2;
  u16* qb  = (u16*)ws; ws += (size_t)8192 * 1024 * 2;
  u16* kb  = (u16*)ws; ws += (size_t)8192 * 1024 * 2;
  u16* vb  = (u16*)ws; ws += (size_t)8192 * 1024 * 2;
  u16* att = (u16*)ws; ws += (size_t)8192 * 1024 * 2;

  k_cvt<<<dim3(8192), dim3(256), 0, stream>>>(x, xb);
  k_tw<<<dim3(16, 16, 4), dim3(256), 0, stream>>>(Wq, Wk, Wv, Wo, wqT, wkT, wvT, woT);
  k_proj<<<dim3(8, 64, 3), dim3(256), 0, stream>>>(xb, wqT, wkT, wvT, qb, kb, vb);
  k_attn<<<dim3(16, 64), dim3(256), 0, stream>>>(qb, kb, vb, att);
  k_out<<<dim3(8, 64), dim3(256), 0, stream>>>(att, woT, out);
}

// Round 3
// 351.856 us; speedup vs baseline: 1.9156x; 1.2580x over previous
//
#include <hip/hip_runtime.h>

typedef unsigned short u16;
typedef unsigned int u32;
typedef __attribute__((ext_vector_type(8))) short bf16x8;
typedef __attribute__((ext_vector_type(4))) float f32x4;
typedef __attribute__((ext_vector_type(16))) float f32x16;

#define L2E 1.44269504088896340736f

__device__ __forceinline__ u16 f2bf(float f) {
  unsigned u = __float_as_uint(f);
  u += 0x7FFF + ((u >> 16) & 1u);
  return (u16)(u >> 16);
}

__device__ __forceinline__ u32 cvtpk(float lo, float hi) {
  u32 r;
  asm("v_cvt_pk_bf16_f32 %0, %1, %2" : "=v"(r) : "v"(lo), "v"(hi));
  return r;
}

__device__ __forceinline__ void gload_lds16(const u16* g, u16* lds) {
  __builtin_amdgcn_global_load_lds(
      (const __attribute__((address_space(1))) void*)g,
      (__attribute__((address_space(3))) void*)lds, 16, 0, 0);
}

// ---------------- convert x (fp32 -> bf16), 4 elems/thread ----------------
__global__ __launch_bounds__(256) void k_cvt(const float* __restrict__ in,
                                             u16* __restrict__ out) {
  const int i = (blockIdx.x * 256 + threadIdx.x) * 4;
  float4 a = *(const float4*)(in + i);
  ushort4 o;
  o.x = f2bf(a.x); o.y = f2bf(a.y); o.z = f2bf(a.z); o.w = f2bf(a.w);
  *(ushort4*)(out + i) = o;
}

// ------------- transpose 1024x1024 fp32 W[k][n] -> bf16 Wt[n][k] -----------
__global__ __launch_bounds__(256) void k_tw(
    const float* __restrict__ w0, const float* __restrict__ w1,
    const float* __restrict__ w2, const float* __restrict__ w3,
    u16* __restrict__ o0, u16* __restrict__ o1,
    u16* __restrict__ o2, u16* __restrict__ o3) {
  __shared__ float t[64][65];
  const float* W = blockIdx.z == 0 ? w0 : blockIdx.z == 1 ? w1 : blockIdx.z == 2 ? w2 : w3;
  u16* O = blockIdx.z == 0 ? o0 : blockIdx.z == 1 ? o1 : blockIdx.z == 2 ? o2 : o3;
  const int nb = blockIdx.x * 64, kb = blockIdx.y * 64;
  const int lx = threadIdx.x & 63, ly = threadIdx.x >> 6;
  for (int r = ly; r < 64; r += 4)
    t[r][lx] = W[(size_t)(kb + r) * 1024 + nb + lx];
  __syncthreads();
  for (int r = ly; r < 64; r += 4)
    O[(size_t)(nb + r) * 1024 + kb + lx] = f2bf(t[lx][r]);
}

// ---------------- 128x128 bf16 GEMM core (m97 structure) -------------------
__device__ __forceinline__ void gemm_core(const u16* __restrict__ Ag,
                                          const u16* __restrict__ Bg,
                                          f32x4 acc[4][4]) {
  __shared__ u16 As[4096], Bs[4096];
  const int tid = threadIdx.x;
  const int lane = tid & 63, wv = tid >> 6;
  const size_t row0 = (size_t)blockIdx.y * 128;
  const size_t col0 = (size_t)blockIdx.x * 128;
  const int rA0 = wv * 32 + (lane >> 2);
  const int rA1 = rA0 + 16;
  const int kk = (lane & 3) * 8;
  const int wr = (wv >> 1) * 64, wc = (wv & 1) * 64;
  const int fr = lane & 15, fk = (lane >> 4) * 8;
#pragma unroll
  for (int m = 0; m < 4; m++)
#pragma unroll
    for (int n = 0; n < 4; n++)
      acc[m][n] = {0.f, 0.f, 0.f, 0.f};

  for (int kt = 0; kt < 32; kt++) {
    const int k0 = kt * 32;
    gload_lds16(Ag + (row0 + rA0) * 1024 + k0 + kk, &As[(wv * 2 + 0) * 512]);
    gload_lds16(Ag + (row0 + rA1) * 1024 + k0 + kk, &As[(wv * 2 + 1) * 512]);
    gload_lds16(Bg + (col0 + rA0) * 1024 + k0 + kk, &Bs[(wv * 2 + 0) * 512]);
    gload_lds16(Bg + (col0 + rA1) * 1024 + k0 + kk, &Bs[(wv * 2 + 1) * 512]);
    __syncthreads();
    bf16x8 af[4], bfr[4];
#pragma unroll
    for (int m = 0; m < 4; m++)
      af[m] = *(const bf16x8*)&As[(wr + m * 16 + fr) * 32 + fk];
#pragma unroll
    for (int n = 0; n < 4; n++)
      bfr[n] = *(const bf16x8*)&Bs[(wc + n * 16 + fr) * 32 + fk];
#pragma unroll
    for (int m = 0; m < 4; m++)
#pragma unroll
      for (int n = 0; n < 4; n++)
        acc[m][n] = __builtin_amdgcn_mfma_f32_16x16x32_bf16(af[m], bfr[n], acc[m][n], 0, 0, 0);
    __syncthreads();
  }
}

// -------- fused projection GEMM: z=0 -> q (scaled by L2E/32), z=1 -> k, z=2 -> vT
__global__ __launch_bounds__(256) void k_proj(
    const u16* __restrict__ xb, const u16* __restrict__ wqT,
    const u16* __restrict__ wkT, const u16* __restrict__ wvT,
    u16* __restrict__ q, u16* __restrict__ k, u16* __restrict__ v) {
  f32x4 acc[4][4];
  const int z = blockIdx.z;
  const u16* Bg = z == 0 ? wqT : z == 1 ? wkT : wvT;
  gemm_core(xb, Bg, acc);
  const int lane = threadIdx.x & 63, wv = threadIdx.x >> 6;
  const int wr = (wv >> 1) * 64, wc = (wv & 1) * 64;
  const int rb = blockIdx.y * 128 + wr + ((lane >> 4) * 4);
  const int cb = blockIdx.x * 128 + wc + (lane & 15);
#pragma unroll
  for (int m = 0; m < 4; m++) {
#pragma unroll
    for (int n = 0; n < 4; n++) {
      const int C = cb + n * 16;
      const int h = C >> 6, d = C & 63;
      if (z == 2) {
        const int R = rb + m * 16;  // 4-aligned
        const int b = R >> 11, nn = R & 2047;
        ushort4 o;
        o.x = f2bf(acc[m][n][0]); o.y = f2bf(acc[m][n][1]);
        o.z = f2bf(acc[m][n][2]); o.w = f2bf(acc[m][n][3]);
        *(ushort4*)&v[(size_t)((b * 16 + h) * 64 + d) * 2048 + nn] = o;
      } else {
        u16* dst = (z == 0) ? q : k;
        // q pre-scaled by (1/sqrt(1024)) * log2(e) so attention can use exp2 directly
        const float s = (z == 0) ? (0.03125f * L2E) : 1.0f;
#pragma unroll
        for (int i = 0; i < 4; i++) {
          const int R = rb + m * 16 + i;
          const int b = R >> 11, nn = R & 2047;
          dst[(size_t)((b * 16 + h) * 2048 + nn) * 64 + d] = f2bf(acc[m][n][i] * s);
        }
      }
    }
  }
}

// ---------------- output GEMM: att(bf16) @ WoT -> fp32 out -----------------
__global__ __launch_bounds__(256) void k_out(const u16* __restrict__ att,
                                             const u16* __restrict__ woT,
                                             float* __restrict__ out) {
  f32x4 acc[4][4];
  gemm_core(att, woT, acc);
  const int lane = threadIdx.x & 63, wv = threadIdx.x >> 6;
  const int wr = (wv >> 1) * 64, wc = (wv & 1) * 64;
  const int rb = blockIdx.y * 128 + wr + ((lane >> 4) * 4);
  const int cb = blockIdx.x * 128 + wc + (lane & 15);
#pragma unroll
  for (int m = 0; m < 4; m++)
#pragma unroll
    for (int n = 0; n < 4; n++)
#pragma unroll
      for (int i = 0; i < 4; i++)
        out[(size_t)(rb + m * 16 + i) * 1024 + cb + n * 16] = acc[m][n][i];
}

// ---------------- flash attention, 32x32 swapped + 2-phase LDS pipeline ----
// grid (16 qtiles, 64 bh), 256 thr = 4 waves; each wave owns 32 q-rows.
// q,k: [bh][n][64] bf16 (q pre-scaled by L2E/32); v: [bh][64][n] bf16.
// Per 64-key tile: K(8KB)+V(8KB) staged to LDS via global_load_lds (shared by
// all 4 waves), double-buffered, XOR-swizzled (pre-swizzled global source +
// swizzled ds_read per rule #21). STAGE(t+1) issues before compute(t).
__global__ __launch_bounds__(256, 2) void k_attn(const u16* __restrict__ q,
                                                 const u16* __restrict__ k,
                                                 const u16* __restrict__ v,
                                                 u16* __restrict__ att) {
  __shared__ u16 SM[16384];  // 2 bufs x (K 4096 + V 4096) u16; epilogue aliases
  const int lane = threadIdx.x & 63, wv = threadIdx.x >> 6;
  const int lo5 = lane & 31, hi = lane >> 5;
  const int r7 = lo5 & 7;
  const int bh = blockIdx.y;
  const int b = bh >> 4, h = bh & 15;
  const int q0w = blockIdx.x * 128 + wv * 32;
  const size_t base = (size_t)bh * 2048 * 64;

  // staging geometry: linear slot l -> row l>>3, chunk l&7; source chunk
  // pre-swizzled so LDS stays linear while reads use chunk^(row&7).
  const int l0 = wv * 64 + lane, l1 = 256 + l0;
  const int sr0 = l0 >> 3, sc0 = ((l0 & 7) ^ (sr0 & 7)) * 8;
  const int sr1 = l1 >> 3, sc1 = ((l1 & 7) ^ (sr1 & 7)) * 8;

  // Q as B-fragments: qb[db] holds Q[q=lo5][d = db*16 + hi*8 + i]
  bf16x8 qb[4];
  {
    const u16* qp = q + base + (size_t)(q0w + lo5) * 64 + hi * 8;
#pragma unroll
    for (int db = 0; db < 4; db++) qb[db] = *(const bf16x8*)(qp + db * 16);
  }

  f32x16 o0, o1;
#pragma unroll
  for (int i = 0; i < 16; i++) { o0[i] = 0.f; o1[i] = 0.f; }
  float m_run = -3.0e38f, l_run = 0.f;

  // prologue: stage tile 0 into buf 0
  {
    u16* Kd = SM;
    u16* Vd = SM + 4096;
    gload_lds16(k + base + (size_t)sr0 * 64 + sc0, Kd + wv * 512);
    gload_lds16(k + base + (size_t)sr1 * 64 + sc1, Kd + 2048 + wv * 512);
    gload_lds16(v + base + (size_t)sr0 * 2048 + sc0, Vd + wv * 512);
    gload_lds16(v + base + (size_t)sr1 * 2048 + sc1, Vd + 2048 + wv * 512);
  }
  __syncthreads();

  int cur = 0;
  for (int kt = 0; kt < 32; kt++) {
    const int kb = kt * 64;
    // ---- stage next tile into buf^1 (async; drained by end-of-tile barrier)
    {
      const int nkb = (kt + 1 < 32 ? kt + 1 : 0) * 64;
      u16* Kd = SM + (cur ^ 1) * 8192;
      u16* Vd = Kd + 4096;
      gload_lds16(k + base + (size_t)(nkb + sr0) * 64 + sc0, Kd + wv * 512);
      gload_lds16(k + base + (size_t)(nkb + sr1) * 64 + sc1, Kd + 2048 + wv * 512);
      gload_lds16(v + base + (size_t)sr0 * 2048 + nkb + sc0, Vd + wv * 512);
      gload_lds16(v + base + (size_t)sr1 * 2048 + nkb + sc1, Vd + 2048 + wv * 512);
    }

    const u16* Kc = SM + cur * 8192;
    const u16* Vc = Kc + 4096;

    // ---- S^T = K · Q^T : col = q (lane&31), row = key
    f32x16 s0, s1;
#pragma unroll
    for (int i = 0; i < 16; i++) { s0[i] = 0.f; s1[i] = 0.f; }
    __builtin_amdgcn_s_setprio(1);
#pragma unroll
    for (int db = 0; db < 4; db++) {
      const int swz = ((db * 2 + hi) ^ r7) << 3;
      const bf16x8 k0 = *(const bf16x8*)&Kc[lo5 * 64 + swz];
      const bf16x8 k1 = *(const bf16x8*)&Kc[(32 + lo5) * 64 + swz];
      s0 = __builtin_amdgcn_mfma_f32_32x32x16_bf16(k0, qb[db], s0, 0, 0, 0);
      s1 = __builtin_amdgcn_mfma_f32_32x32x16_bf16(k1, qb[db], s1, 0, 0, 0);
    }
    __builtin_amdgcn_s_setprio(0);

    // ---- online softmax (log2 domain; q pre-scaled by L2E)
    float t[16];
#pragma unroll
    for (int i = 0; i < 16; i++) t[i] = fmaxf(s0[i], s1[i]);
#pragma unroll
    for (int off = 8; off; off >>= 1)
#pragma unroll
      for (int i = 0; i < off; i++) t[i] = fmaxf(t[i], t[i + off]);
    const float tmax = fmaxf(t[0], __shfl_xor(t[0], 32, 64));

    // T13 defer-max: skip rescale while per-tile growth <= 8 (P bounded 2^8)
    const bool skip = __all(tmax - m_run <= 8.0f);
    float sc = 1.0f;
    if (!skip) {
      const float mnew = fmaxf(m_run, tmax);
      sc = exp2f(m_run - mnew);
      m_run = mnew;
    }

    float p0[16], p1[16];
#pragma unroll
    for (int i = 0; i < 16; i++) {
      p0[i] = exp2f(s0[i] - m_run);
      p1[i] = exp2f(s1[i] - m_run);
    }
    float u[16];
#pragma unroll
    for (int i = 0; i < 16; i++) u[i] = p0[i] + p1[i];
#pragma unroll
    for (int off = 8; off; off >>= 1)
#pragma unroll
      for (int i = 0; i < off; i++) u[i] += u[i + off];
    const float rs = u[0] + __shfl_xor(u[0], 32, 64);
    l_run = l_run * sc + rs;
    if (!skip) {
#pragma unroll
      for (int i = 0; i < 16; i++) { o0[i] *= sc; o1[i] *= sc; }
    }

    // ---- pack P -> bf16 B-fragments pa[ks]: P[key = ks*16+hi*8+i][q=lo5]
    bf16x8 pa[4];
#pragma unroll
    for (int kh = 0; kh < 2; kh++) {
      const float* pp = kh ? p1 : p0;
#pragma unroll
      for (int kl = 0; kl < 2; kl++) {
        const int r0 = kl * 8;
        const u32 a0 = cvtpk(pp[r0 + 0], pp[r0 + 1]);
        const u32 a1 = cvtpk(pp[r0 + 2], pp[r0 + 3]);
        const u32 b0 = cvtpk(pp[r0 + 4], pp[r0 + 5]);
        const u32 b1 = cvtpk(pp[r0 + 6], pp[r0 + 7]);
        const u32 a0x = (u32)__shfl_xor((int)a0, 32, 64);
        const u32 a1x = (u32)__shfl_xor((int)a1, 32, 64);
        const u32 b0x = (u32)__shfl_xor((int)b0, 32, 64);
        const u32 b1x = (u32)__shfl_xor((int)b1, 32, 64);
        union { u32 w[4]; bf16x8 v; } U;
        U.w[0] = hi ? b0x : a0;
        U.w[1] = hi ? b1x : a1;
        U.w[2] = hi ? b0 : a0x;
        U.w[3] = hi ? b1 : a1x;
        pa[kh * 2 + kl] = U.v;
      }
    }

    // ---- O^T += V^T · P : rows = d, col = q
    __builtin_amdgcn_s_setprio(1);
#pragma unroll
    for (int ks = 0; ks < 4; ks++) {
      const int swz = ((ks * 2 + hi) ^ r7) << 3;
      const bf16x8 v0 = *(const bf16x8*)&Vc[lo5 * 64 + swz];
      const bf16x8 v1 = *(const bf16x8*)&Vc[(32 + lo5) * 64 + swz];
      o0 = __builtin_amdgcn_mfma_f32_32x32x16_bf16(v0, pa[ks], o0, 0, 0, 0);
      o1 = __builtin_amdgcn_mfma_f32_32x32x16_bf16(v1, pa[ks], o1, 0, 0, 0);
    }
    __builtin_amdgcn_s_setprio(0);

    __syncthreads();  // next-tile staging complete + this tile's reads done
    cur ^= 1;
  }

  // ---- epilogue: normalize, transpose via per-wave LDS, coalesced store
  // (aliases staging buffer; all waves past final barrier, per-wave regions)
  const float linv = 1.0f / l_run;
  u16* W = SM + wv * 2176;
#pragma unroll
  for (int r = 0; r < 16; r++) {
    const int dd = (r & 3) + 8 * (r >> 2) + 4 * hi;
    W[lo5 * 68 + dd] = f2bf(o0[r] * linv);
    W[lo5 * 68 + 32 + dd] = f2bf(o1[r] * linv);
  }
  const int q_loc = lane >> 1, dh = (lane & 1) * 32;
  u16* dst = att + (size_t)(b * 2048 + q0w + q_loc) * 1024 + h * 64 + dh;
#pragma unroll
  for (int c = 0; c < 4; c++) {
    bf16x8 val = *(const bf16x8*)&W[q_loc * 68 + dh + c * 8];
    *(bf16x8*)(dst + c * 8) = val;
  }
}

extern "C" void kernel_launch(void* const* d_in, const int* in_sizes, int n_in,
                              void* d_out, int out_size, void* d_ws, size_t ws_size,
                              hipStream_t stream) {
  const float* x  = (const float*)d_in[0];
  const float* Wq = (const float*)d_in[1];
  const float* Wk = (const float*)d_in[2];
  const float* Wv = (const float*)d_in[3];
  const float* Wo = (const float*)d_in[4];
  float* out = (float*)d_out;

  char* ws = (char*)d_ws;
  u16* xb  = (u16*)ws; ws += (size_t)8192 * 1024 * 2;
  u16* wqT = (u16*)ws; ws += (size_t)1024 * 1024 * 2;
  u16* wkT = (u16*)ws; ws += (size_t)1024 * 1024 * 2;
  u16* wvT = (u16*)ws; ws += (size_t)1024 * 1024 * 2;
  u16* woT = (u16*)ws; ws += (size_t)1024 * 1024 * 2;
  u16* qb  = (u16*)ws; ws += (size_t)8192 * 1024 * 2;
  u16* kb  = (u16*)ws; ws += (size_t)8192 * 1024 * 2;
  u16* vb  = (u16*)ws; ws += (size_t)8192 * 1024 * 2;
  u16* att = (u16*)ws; ws += (size_t)8192 * 1024 * 2;

  k_cvt<<<dim3(8192), dim3(256), 0, stream>>>(x, xb);
  k_tw<<<dim3(16, 16, 4), dim3(256), 0, stream>>>(Wq, Wk, Wv, Wo, wqT, wkT, wvT, woT);
  k_proj<<<dim3(8, 64, 3), dim3(256), 0, stream>>>(xb, wqT, wkT, wvT, qb, kb, vb);
  k_attn<<<dim3(16, 64), dim3(256), 0, stream>>>(qb, kb, vb, att);
  k_out<<<dim3(8, 64), dim3(256), 0, stream>>>(att, woT, out);
}

// Round 6
// 316.498 us; speedup vs baseline: 2.1296x; 1.1117x over previous
//
#include <hip/hip_runtime.h>

typedef unsigned short u16;
typedef unsigned int u32;
typedef __attribute__((ext_vector_type(8))) short bf16x8;
typedef __attribute__((ext_vector_type(4))) float f32x4;
typedef __attribute__((ext_vector_type(16))) float f32x16;

#define L2E 1.44269504088896340736f

__device__ __forceinline__ u16 f2bf(float f) {
  unsigned u = __float_as_uint(f);
  u += 0x7FFF + ((u >> 16) & 1u);
  return (u16)(u >> 16);
}

__device__ __forceinline__ u32 cvtpk(float lo, float hi) {
  u32 r;
  asm("v_cvt_pk_bf16_f32 %0, %1, %2" : "=v"(r) : "v"(lo), "v"(hi));
  return r;
}

__device__ __forceinline__ void gload_lds16(const u16* g, u16* lds) {
  __builtin_amdgcn_global_load_lds(
      (const __attribute__((address_space(1))) void*)g,
      (__attribute__((address_space(3))) void*)lds, 16, 0, 0);
}

// ---------------- convert x (fp32 -> bf16), 4 elems/thread ----------------
__global__ __launch_bounds__(256) void k_cvt(const float* __restrict__ in,
                                             u16* __restrict__ out) {
  const int i = (blockIdx.x * 256 + threadIdx.x) * 4;
  float4 a = *(const float4*)(in + i);
  ushort4 o;
  o.x = f2bf(a.x); o.y = f2bf(a.y); o.z = f2bf(a.z); o.w = f2bf(a.w);
  *(ushort4*)(out + i) = o;
}

// ------------- transpose 1024x1024 fp32 W[k][n] -> bf16 Wt[n][k] -----------
__global__ __launch_bounds__(256) void k_tw(
    const float* __restrict__ w0, const float* __restrict__ w1,
    const float* __restrict__ w2, const float* __restrict__ w3,
    u16* __restrict__ o0, u16* __restrict__ o1,
    u16* __restrict__ o2, u16* __restrict__ o3) {
  __shared__ float t[64][65];
  const float* W = blockIdx.z == 0 ? w0 : blockIdx.z == 1 ? w1 : blockIdx.z == 2 ? w2 : w3;
  u16* O = blockIdx.z == 0 ? o0 : blockIdx.z == 1 ? o1 : blockIdx.z == 2 ? o2 : o3;
  const int nb = blockIdx.x * 64, kb = blockIdx.y * 64;
  const int lx = threadIdx.x & 63, ly = threadIdx.x >> 6;
  for (int r = ly; r < 64; r += 4)
    t[r][lx] = W[(size_t)(kb + r) * 1024 + nb + lx];
  __syncthreads();
  for (int r = ly; r < 64; r += 4)
    O[(size_t)(nb + r) * 1024 + kb + lx] = f2bf(t[lx][r]);
}

// ---------------- 128x128 bf16 GEMM core (m97 structure) -------------------
__device__ __forceinline__ void gemm_core(const u16* __restrict__ Ag,
                                          const u16* __restrict__ Bg,
                                          f32x4 acc[4][4]) {
  __shared__ u16 As[4096], Bs[4096];
  const int tid = threadIdx.x;
  const int lane = tid & 63, wv = tid >> 6;
  const size_t row0 = (size_t)blockIdx.y * 128;
  const size_t col0 = (size_t)blockIdx.x * 128;
  const int rA0 = wv * 32 + (lane >> 2);
  const int rA1 = rA0 + 16;
  const int kk = (lane & 3) * 8;
  const int wr = (wv >> 1) * 64, wc = (wv & 1) * 64;
  const int fr = lane & 15, fk = (lane >> 4) * 8;
#pragma unroll
  for (int m = 0; m < 4; m++)
#pragma unroll
    for (int n = 0; n < 4; n++)
      acc[m][n] = {0.f, 0.f, 0.f, 0.f};

  for (int kt = 0; kt < 32; kt++) {
    const int k0 = kt * 32;
    gload_lds16(Ag + (row0 + rA0) * 1024 + k0 + kk, &As[(wv * 2 + 0) * 512]);
    gload_lds16(Ag + (row0 + rA1) * 1024 + k0 + kk, &As[(wv * 2 + 1) * 512]);
    gload_lds16(Bg + (col0 + rA0) * 1024 + k0 + kk, &Bs[(wv * 2 + 0) * 512]);
    gload_lds16(Bg + (col0 + rA1) * 1024 + k0 + kk, &Bs[(wv * 2 + 1) * 512]);
    __syncthreads();
    bf16x8 af[4], bfr[4];
#pragma unroll
    for (int m = 0; m < 4; m++)
      af[m] = *(const bf16x8*)&As[(wr + m * 16 + fr) * 32 + fk];
#pragma unroll
    for (int n = 0; n < 4; n++)
      bfr[n] = *(const bf16x8*)&Bs[(wc + n * 16 + fr) * 32 + fk];
#pragma unroll
    for (int m = 0; m < 4; m++)
#pragma unroll
      for (int n = 0; n < 4; n++)
        acc[m][n] = __builtin_amdgcn_mfma_f32_16x16x32_bf16(af[m], bfr[n], acc[m][n], 0, 0, 0);
    __syncthreads();
  }
}

// -------- fused projection GEMM: z=0 -> q (scaled by L2E/32), z=1 -> K tiles,
// z=2 -> V tiles. K tile layout (per bh, per 64-key tile t):
//   u16 off = bh*131072 + t*4096 + (d>>3)*512 + (n&63)*8 + (d&7)
// V tile layout:
//   u16 off = bh*131072 + t*4096 + ((n&63)>>3)*512 + d*8 + (n&7)
__global__ __launch_bounds__(256) void k_proj(
    const u16* __restrict__ xb, const u16* __restrict__ wqT,
    const u16* __restrict__ wkT, const u16* __restrict__ wvT,
    u16* __restrict__ q, u16* __restrict__ k, u16* __restrict__ v) {
  f32x4 acc[4][4];
  const int z = blockIdx.z;
  const u16* Bg = z == 0 ? wqT : z == 1 ? wkT : wvT;
  gemm_core(xb, Bg, acc);
  const int lane = threadIdx.x & 63, wv = threadIdx.x >> 6;
  const int wr = (wv >> 1) * 64, wc = (wv & 1) * 64;
  const int rb = blockIdx.y * 128 + wr + ((lane >> 4) * 4);
  const int cb = blockIdx.x * 128 + wc + (lane & 15);
#pragma unroll
  for (int m = 0; m < 4; m++) {
#pragma unroll
    for (int n = 0; n < 4; n++) {
      const int C = cb + n * 16;
      const int h = C >> 6, d = C & 63;
      if (z == 2) {
        const int R = rb + m * 16;  // 4-aligned
        const int b = R >> 11, nn = R & 2047;
        const int bh = b * 16 + h;
        ushort4 o;
        o.x = f2bf(acc[m][n][0]); o.y = f2bf(acc[m][n][1]);
        o.z = f2bf(acc[m][n][2]); o.w = f2bf(acc[m][n][3]);
        const size_t off = (size_t)bh * 131072 + (size_t)(nn >> 6) * 4096 +
                           ((nn & 63) >> 3) * 512 + d * 8 + (nn & 7);
        *(ushort4*)&v[off] = o;
      } else if (z == 1) {
#pragma unroll
        for (int i = 0; i < 4; i++) {
          const int R = rb + m * 16 + i;
          const int b = R >> 11, nn = R & 2047;
          const int bh = b * 16 + h;
          const size_t off = (size_t)bh * 131072 + (size_t)(nn >> 6) * 4096 +
                             (d >> 3) * 512 + (nn & 63) * 8 + (d & 7);
          k[off] = f2bf(acc[m][n][i]);
        }
      } else {
        // q pre-scaled by (1/sqrt(1024)) * log2(e) so attention uses exp2 directly
        const float s = 0.03125f * L2E;
#pragma unroll
        for (int i = 0; i < 4; i++) {
          const int R = rb + m * 16 + i;
          const int b = R >> 11, nn = R & 2047;
          q[(size_t)((b * 16 + h) * 2048 + nn) * 64 + d] = f2bf(acc[m][n][i] * s);
        }
      }
    }
  }
}

// ---------------- output GEMM: att(bf16) @ WoT -> fp32 out -----------------
__global__ __launch_bounds__(256) void k_out(const u16* __restrict__ att,
                                             const u16* __restrict__ woT,
                                             float* __restrict__ out) {
  f32x4 acc[4][4];
  gemm_core(att, woT, acc);
  const int lane = threadIdx.x & 63, wv = threadIdx.x >> 6;
  const int wr = (wv >> 1) * 64, wc = (wv & 1) * 64;
  const int rb = blockIdx.y * 128 + wr + ((lane >> 4) * 4);
  const int cb = blockIdx.x * 128 + wc + (lane & 15);
#pragma unroll
  for (int m = 0; m < 4; m++)
#pragma unroll
    for (int n = 0; n < 4; n++)
#pragma unroll
      for (int i = 0; i < 4; i++)
        out[(size_t)(rb + m * 16 + i) * 1024 + cb + n * 16] = acc[m][n][i];
}

// ---------------- flash attention, 32x32 swapped, chunk-major LDS ----------
// grid (16 qtiles, 64 bh), 256 thr = 4 waves; each wave owns 32 q-rows.
// q: [bh][n][64] bf16 (pre-scaled by L2E/32). K/V: tile-blocked chunk-major
// (see k_proj) so staging is 4 linear 1KB global_load_lds per tile and every
// ds_read_b128 is the linear conflict-free pattern (base lo5*8+hi*512 +
// compile-time offset). Double-buffered, stage(t+1) before compute(t).
// Cross-half exchanges use __shfl_xor(.,32) (R3-proven; permlane asm was the
// R4 failure suspect and is reverted for isolation).
__global__ __launch_bounds__(256, 2) void k_attn(const u16* __restrict__ qg,
                                                 const u16* __restrict__ kg,
                                                 const u16* __restrict__ vg,
                                                 u16* __restrict__ att) {
  __shared__ u16 SM[16384];  // 2 bufs x (K 4096 + V 4096) u16; epilogue aliases
  const int tid = threadIdx.x;
  const int lane = tid & 63, wv = tid >> 6;
  const int lo5 = lane & 31, hi = lane >> 5;
  const int bh = blockIdx.y;
  const int b = bh >> 4, h = bh & 15;
  const int q0w = blockIdx.x * 128 + wv * 32;
  const size_t qbase = (size_t)bh * 2048 * 64;
  const u16* kt0 = kg + (size_t)bh * 131072;
  const u16* vt0 = vg + (size_t)bh * 131072;

  // Q as B-fragments: qb[db] holds Q[q=lo5][d = db*16 + hi*8 + i]
  bf16x8 qb[4];
  {
    const u16* qp = qg + qbase + (size_t)(q0w + lo5) * 64 + hi * 8;
#pragma unroll
    for (int db = 0; db < 4; db++) qb[db] = *(const bf16x8*)(qp + db * 16);
  }

  f32x16 o0, o1;
#pragma unroll
  for (int i = 0; i < 16; i++) { o0[i] = 0.f; o1[i] = 0.f; }
  float m_run = -3.0e38f;
  float l16[16];
#pragma unroll
  for (int i = 0; i < 16; i++) l16[i] = 0.f;

  // prologue: stage tile 0 into buf 0 (4 linear 1KB loads)
  gload_lds16(kt0 + (size_t)tid * 8, SM + wv * 512);
  gload_lds16(kt0 + (size_t)(256 + tid) * 8, SM + 2048 + wv * 512);
  gload_lds16(vt0 + (size_t)tid * 8, SM + 4096 + wv * 512);
  gload_lds16(vt0 + (size_t)(256 + tid) * 8, SM + 6144 + wv * 512);
  __syncthreads();

  int cur = 0;
  for (int t = 0; t < 32; t++) {
    // ---- stage next tile into buf^1 (async; drained by end-of-tile barrier)
    {
      const int nt = (t + 1) & 31;
      const u16* ks = kt0 + (size_t)nt * 4096;
      const u16* vs = vt0 + (size_t)nt * 4096;
      u16* Kd = SM + (cur ^ 1) * 8192;
      gload_lds16(ks + (size_t)tid * 8, Kd + wv * 512);
      gload_lds16(ks + (size_t)(256 + tid) * 8, Kd + 2048 + wv * 512);
      gload_lds16(vs + (size_t)tid * 8, Kd + 4096 + wv * 512);
      gload_lds16(vs + (size_t)(256 + tid) * 8, Kd + 6144 + wv * 512);
    }

    const u16* Kc = SM + cur * 8192 + hi * 512 + lo5 * 8;
    const u16* Vc = Kc + 4096;

    // ---- S^T = K · Q^T : col = q (lane&31), row = key
    f32x16 s0, s1;
#pragma unroll
    for (int i = 0; i < 16; i++) { s0[i] = 0.f; s1[i] = 0.f; }
    __builtin_amdgcn_s_setprio(1);
#pragma unroll
    for (int db = 0; db < 4; db++) {
      const bf16x8 k0 = *(const bf16x8*)&Kc[db * 1024];        // keys 0..31
      const bf16x8 k1 = *(const bf16x8*)&Kc[db * 1024 + 256];  // keys 32..63
      s0 = __builtin_amdgcn_mfma_f32_32x32x16_bf16(k0, qb[db], s0, 0, 0, 0);
      s1 = __builtin_amdgcn_mfma_f32_32x32x16_bf16(k1, qb[db], s1, 0, 0, 0);
    }
    __builtin_amdgcn_s_setprio(0);

    // ---- online softmax (log2 domain; q pre-scaled by L2E)
    float tmx[16];
#pragma unroll
    for (int i = 0; i < 16; i++) tmx[i] = fmaxf(s0[i], s1[i]);
#pragma unroll
    for (int off = 8; off; off >>= 1)
#pragma unroll
      for (int i = 0; i < off; i++) tmx[i] = fmaxf(tmx[i], tmx[i + off]);
    const float tmax = fmaxf(tmx[0], __shfl_xor(tmx[0], 32, 64));

    // T13 defer-max: skip rescale while per-tile growth <= 8 (P bounded 2^8)
    const bool skip = __all(tmax - m_run <= 8.0f);
    if (!skip) {
      const float mnew = fmaxf(m_run, tmax);
      const float sc = __builtin_amdgcn_exp2f(m_run - mnew);
      m_run = mnew;
#pragma unroll
      for (int i = 0; i < 16; i++) {
        l16[i] *= sc; o0[i] *= sc; o1[i] *= sc;
      }
    }

    float p0[16], p1[16];
#pragma unroll
    for (int i = 0; i < 16; i++) {
      p0[i] = __builtin_amdgcn_exp2f(s0[i] - m_run);
      p1[i] = __builtin_amdgcn_exp2f(s1[i] - m_run);
      l16[i] += p0[i] + p1[i];
    }

    // ---- pack P -> bf16 B-frags pa[ks]: P[key = ks*16+hi*8+i][q=lo5]
    // (cvt_pk + shfl_xor cross-half exchange — R3-proven)
    bf16x8 pa[4];
#pragma unroll
    for (int kh = 0; kh < 2; kh++) {
      const float* pp = kh ? p1 : p0;
#pragma unroll
      for (int kl = 0; kl < 2; kl++) {
        const int r0 = kl * 8;
        const u32 a0 = cvtpk(pp[r0 + 0], pp[r0 + 1]);
        const u32 a1 = cvtpk(pp[r0 + 2], pp[r0 + 3]);
        const u32 b0 = cvtpk(pp[r0 + 4], pp[r0 + 5]);
        const u32 b1 = cvtpk(pp[r0 + 6], pp[r0 + 7]);
        const u32 a0x = (u32)__shfl_xor((int)a0, 32, 64);
        const u32 a1x = (u32)__shfl_xor((int)a1, 32, 64);
        const u32 b0x = (u32)__shfl_xor((int)b0, 32, 64);
        const u32 b1x = (u32)__shfl_xor((int)b1, 32, 64);
        union { u32 w[4]; bf16x8 v; } U;
        U.w[0] = hi ? b0x : a0;
        U.w[1] = hi ? b1x : a1;
        U.w[2] = hi ? b0 : a0x;
        U.w[3] = hi ? b1 : a1x;
        pa[kh * 2 + kl] = U.v;
      }
    }

    // ---- O^T += V^T · P : rows = d, col = q
    __builtin_amdgcn_s_setprio(1);
#pragma unroll
    for (int ks = 0; ks < 4; ks++) {
      const bf16x8 v0 = *(const bf16x8*)&Vc[ks * 1024];        // d = lo5
      const bf16x8 v1 = *(const bf16x8*)&Vc[ks * 1024 + 256];  // d = 32+lo5
      o0 = __builtin_amdgcn_mfma_f32_32x32x16_bf16(v0, pa[ks], o0, 0, 0, 0);
      o1 = __builtin_amdgcn_mfma_f32_32x32x16_bf16(v1, pa[ks], o1, 0, 0, 0);
    }
    __builtin_amdgcn_s_setprio(0);

    __syncthreads();  // next-tile staging complete + this tile's reads done
    cur ^= 1;
  }

  // ---- final l reduction: 16-reg tree + cross-half add
  float ls[8];
#pragma unroll
  for (int i = 0; i < 8; i++) ls[i] = l16[i] + l16[i + 8];
#pragma unroll
  for (int off = 4; off; off >>= 1)
#pragma unroll
    for (int i = 0; i < off; i++) ls[i] += ls[i + off];
  const float lsum = ls[0] + __shfl_xor(ls[0], 32, 64);
  const float linv = 1.0f / lsum;

  // ---- epilogue: normalize, transpose via per-wave LDS, coalesced store
  u16* W = SM + wv * 2176;
#pragma unroll
  for (int r = 0; r < 16; r++) {
    const int dd = (r & 3) + 8 * (r >> 2) + 4 * hi;
    W[lo5 * 68 + dd] = f2bf(o0[r] * linv);
    W[lo5 * 68 + 32 + dd] = f2bf(o1[r] * linv);
  }
  const int q_loc = lane >> 1, dh = (lane & 1) * 32;
  u16* dst = att + (size_t)(b * 2048 + q0w + q_loc) * 1024 + h * 64 + dh;
#pragma unroll
  for (int c = 0; c < 4; c++) {
    bf16x8 val = *(const bf16x8*)&W[q_loc * 68 + dh + c * 8];
    *(bf16x8*)(dst + c * 8) = val;
  }
}

extern "C" void kernel_launch(void* const* d_in, const int* in_sizes, int n_in,
                              void* d_out, int out_size, void* d_ws, size_t ws_size,
                              hipStream_t stream) {
  const float* x  = (const float*)d_in[0];
  const float* Wq = (const float*)d_in[1];
  const float* Wk = (const float*)d_in[2];
  const float* Wv = (const float*)d_in[3];
  const float* Wo = (const float*)d_in[4];
  float* out = (float*)d_out;

  char* ws = (char*)d_ws;
  u16* xb  = (u16*)ws; ws += (size_t)8192 * 1024 * 2;
  u16* wqT = (u16*)ws; ws += (size_t)1024 * 1024 * 2;
  u16* wkT = (u16*)ws; ws += (size_t)1024 * 1024 * 2;
  u16* wvT = (u16*)ws; ws += (size_t)1024 * 1024 * 2;
  u16* woT = (u16*)ws; ws += (size_t)1024 * 1024 * 2;
  u16* qb  = (u16*)ws; ws += (size_t)8192 * 1024 * 2;
  u16* kb  = (u16*)ws; ws += (size_t)8192 * 1024 * 2;
  u16* vb  = (u16*)ws; ws += (size_t)8192 * 1024 * 2;
  u16* att = (u16*)ws; ws += (size_t)8192 * 1024 * 2;

  k_cvt<<<dim3(8192), dim3(256), 0, stream>>>(x, xb);
  k_tw<<<dim3(16, 16, 4), dim3(256), 0, stream>>>(Wq, Wk, Wv, Wo, wqT, wkT, wvT, woT);
  k_proj<<<dim3(8, 64, 3), dim3(256), 0, stream>>>(xb, wqT, wkT, wvT, qb, kb, vb);
  k_attn<<<dim3(16, 64), dim3(256), 0, stream>>>(qb, kb, vb, att);
  k_out<<<dim3(8, 64), dim3(256), 0, stream>>>(att, woT, out);
}

// Round 7
// 283.932 us; speedup vs baseline: 2.3739x; 1.1147x over previous
//
#include <hip/hip_runtime.h>

typedef unsigned short u16;
typedef unsigned int u32;
typedef __attribute__((ext_vector_type(8))) short bf16x8;
typedef __attribute__((ext_vector_type(4))) float f32x4;
typedef __attribute__((ext_vector_type(16))) float f32x16;

#define L2E 1.44269504088896340736f

// ---- blocked layouts (all u16 offsets) ----
// A_blk (8192x1024 matrices: xb, att): kt=k>>5, c=(k>>3)&3, e=k&7, hb=n>>7, rl=n&127
//   off = kt*262144 + hb*4096 + c*1024 + rl*8 + e
// B_blk wqkv (3072 rows = Wq^T|Wk^T|Wv^T): off = kt*98304 + (ncol>>7)*4096 + c*1024 + (ncol&127)*8 + e
// B_blk wo (1024 rows):                    off = kt*32768 + (ncol>>7)*4096 + c*1024 + (ncol&127)*8 + e
// attn K tile (per bh, per 64-key tile t): off = bh*131072 + t*4096 + (d>>3)*512 + (nn&63)*8 + (d&7)
// attn V tile:                             off = bh*131072 + t*4096 + ((nn&63)>>3)*512 + d*8 + (nn&7)

__device__ __forceinline__ u16 f2bf(float f) {
  unsigned u = __float_as_uint(f);
  u += 0x7FFF + ((u >> 16) & 1u);
  return (u16)(u >> 16);
}

__device__ __forceinline__ u32 cvtpk(float lo, float hi) {
  u32 r;
  asm("v_cvt_pk_bf16_f32 %0, %1, %2" : "=v"(r) : "v"(lo), "v"(hi));
  return r;
}

__device__ __forceinline__ void gload_lds16(const u16* g, u16* lds) {
  __builtin_amdgcn_global_load_lds(
      (const __attribute__((address_space(1))) void*)g,
      (__attribute__((address_space(3))) void*)lds, 16, 0, 0);
}

// ---------------- convert x (fp32) -> A_blk bf16 ---------------------------
__global__ __launch_bounds__(256) void k_cvt(const float* __restrict__ in,
                                             u16* __restrict__ out) {
  const int i = (blockIdx.x * 256 + threadIdx.x) * 4;
  const int n = i >> 10, kk = i & 1023;
  float4 a = *(const float4*)(in + i);
  ushort4 o;
  o.x = f2bf(a.x); o.y = f2bf(a.y); o.z = f2bf(a.z); o.w = f2bf(a.w);
  const size_t off = (size_t)(kk >> 5) * 262144 + (size_t)(n >> 7) * 4096 +
                     ((kk >> 3) & 3) * 1024 + (n & 127) * 8 + (kk & 7);
  *(ushort4*)(out + off) = o;
}

// ---- transpose W (fp32 [k][n]) -> blocked bf16 W^T; z<3 -> wqkv, z=3 -> wo
__global__ __launch_bounds__(256) void k_tw(
    const float* __restrict__ w0, const float* __restrict__ w1,
    const float* __restrict__ w2, const float* __restrict__ w3,
    u16* __restrict__ wqkv, u16* __restrict__ wo) {
  __shared__ float t[64][65];
  const int z = blockIdx.z;
  const float* W = z == 0 ? w0 : z == 1 ? w1 : z == 2 ? w2 : w3;
  const int nb = blockIdx.x * 64, kb = blockIdx.y * 64;
  const int lx = threadIdx.x & 63, ly = threadIdx.x >> 6;
  for (int r = ly; r < 64; r += 4)
    t[r][lx] = W[(size_t)(kb + r) * 1024 + nb + lx];
  __syncthreads();
  const int kk = kb + lx;
  for (int r = ly; r < 64; r += 4) {
    const int n = nb + r;
    const u16 val = f2bf(t[lx][r]);
    if (z < 3) {
      const size_t off = (size_t)(kk >> 5) * 98304 + (size_t)(z * 8 + (n >> 7)) * 4096 +
                         ((kk >> 3) & 3) * 1024 + (n & 127) * 8 + (kk & 7);
      wqkv[off] = val;
    } else {
      const size_t off = (size_t)(kk >> 5) * 32768 + (size_t)(n >> 7) * 4096 +
                         ((kk >> 3) & 3) * 1024 + (n & 127) * 8 + (kk & 7);
      wo[off] = val;
    }
  }
}

// ---------------- 128x256 GEMM, counted-vmcnt triple-buffer pipeline -------
// 512 thr = 8 waves (2M x 4N); per-wave 64x64 out (4x4 frags 16x16x32).
// A,B in blocked chunk-major -> linear staging + conflict-free ds_read_b128.
// Schedule per K-step: stage(t+2) | ds_read frags(t) | lgkmcnt(0) | MFMA |
// vmcnt(3) [t+1 complete, t+2 in flight] | s_barrier. Never drains to 0.
// MODE 0: proj (B = wqkv concat, N=3072, z=bn>>2 -> q/k/v epilogues)
// MODE 1: out  (B = wo, N=1024, fp32 C)
template <int MODE>
__global__ __launch_bounds__(512) void k_mm(const u16* __restrict__ Ag,
                                            const u16* __restrict__ Bg,
                                            u16* __restrict__ qo,
                                            u16* __restrict__ ko,
                                            u16* __restrict__ vo,
                                            float* __restrict__ outp) {
  __shared__ u16 SM[3 * 12288];  // 3 bufs x (A 4096 + B 8192) u16 = 72 KB
  const int tid = threadIdx.x, lane = tid & 63, wv = tid >> 6;
  const int wm = wv >> 2, wn = wv & 3;
  const int fr = lane & 15, hi = lane >> 4;
  const int bn = blockIdx.x, bm = blockIdx.y;
  const int PKB = (MODE == 0) ? 98304 : 32768;
  const u16* Asrc = Ag + (size_t)bm * 4096;
  const u16* Bsrc = Bg + (size_t)(bn * 2) * 4096;

  f32x4 acc[4][4];
#pragma unroll
  for (int m = 0; m < 4; m++)
#pragma unroll
    for (int n = 0; n < 4; n++) acc[m][n] = {0.f, 0.f, 0.f, 0.f};

  int aoff[4], boff[4];
#pragma unroll
  for (int m = 0; m < 4; m++)
    aoff[m] = hi * 1024 + (wm * 64 + m * 16 + fr) * 8;
#pragma unroll
  for (int n = 0; n < 4; n++) {
    const int col = wn * 64 + n * 16 + fr;
    boff[n] = 4096 + (col >> 7) * 4096 + hi * 1024 + (col & 127) * 8;
  }

  // prologue: stage tiles 0,1
#pragma unroll
  for (int p = 0; p < 2; p++) {
    u16* D = SM + p * 12288;
    const u16* As = Asrc + (size_t)p * 262144;
    const u16* Bs = Bsrc + (size_t)p * PKB;
    gload_lds16(As + tid * 8, D + wv * 512);
    gload_lds16(Bs + tid * 8, D + 4096 + wv * 512);
    gload_lds16(Bs + 4096 + tid * 8, D + 8192 + wv * 512);
  }
  asm volatile("s_waitcnt vmcnt(3)" ::: "memory");  // tile0 complete
  __builtin_amdgcn_s_barrier();
  __builtin_amdgcn_sched_barrier(0);

  int cur = 0, stg = 2;
  for (int t = 0; t < 32; t++) {
    {  // stage tile t+2 into slot stg
      const int nt = (t + 2) & 31;
      u16* D = SM + stg * 12288;
      const u16* As = Asrc + (size_t)nt * 262144;
      const u16* Bs = Bsrc + (size_t)nt * PKB;
      gload_lds16(As + tid * 8, D + wv * 512);
      gload_lds16(Bs + tid * 8, D + 4096 + wv * 512);
      gload_lds16(Bs + 4096 + tid * 8, D + 8192 + wv * 512);
    }
    const u16* buf = SM + cur * 12288;
    bf16x8 af[4], bfr[4];
#pragma unroll
    for (int m = 0; m < 4; m++) af[m] = *(const bf16x8*)&buf[aoff[m]];
#pragma unroll
    for (int n = 0; n < 4; n++) bfr[n] = *(const bf16x8*)&buf[boff[n]];
    asm volatile("s_waitcnt lgkmcnt(0)" ::: "memory");
    __builtin_amdgcn_sched_barrier(0);
    __builtin_amdgcn_s_setprio(1);
#pragma unroll
    for (int m = 0; m < 4; m++)
#pragma unroll
      for (int n = 0; n < 4; n++)
        acc[m][n] = __builtin_amdgcn_mfma_f32_16x16x32_bf16(af[m], bfr[n], acc[m][n], 0, 0, 0);
    __builtin_amdgcn_s_setprio(0);
    asm volatile("s_waitcnt vmcnt(3)" ::: "memory");  // tile t+1 complete
    __builtin_amdgcn_s_barrier();
    __builtin_amdgcn_sched_barrier(0);
    cur = (cur == 2) ? 0 : cur + 1;
    stg = (stg == 2) ? 0 : stg + 1;
  }

  // ---- epilogue ----
  const int rb = bm * 128 + wm * 64 + hi * 4;
  if (MODE == 1) {
#pragma unroll
    for (int m = 0; m < 4; m++)
#pragma unroll
      for (int n = 0; n < 4; n++) {
        const int C = bn * 256 + wn * 64 + n * 16 + fr;
#pragma unroll
        for (int i = 0; i < 4; i++)
          outp[(size_t)(rb + m * 16 + i) * 1024 + C] = acc[m][n][i];
      }
  } else {
    const int z = bn >> 2;
#pragma unroll
    for (int m = 0; m < 4; m++) {
#pragma unroll
      for (int n = 0; n < 4; n++) {
        const int C = (bn & 3) * 256 + wn * 64 + n * 16 + fr;
        const int h = C >> 6, d = C & 63;
        if (z == 2) {
          const int R = rb + m * 16;  // 4-aligned
          const int b = R >> 11, nn = R & 2047;
          const int bh = b * 16 + h;
          ushort4 o;
          o.x = f2bf(acc[m][n][0]); o.y = f2bf(acc[m][n][1]);
          o.z = f2bf(acc[m][n][2]); o.w = f2bf(acc[m][n][3]);
          const size_t off = (size_t)bh * 131072 + (size_t)(nn >> 6) * 4096 +
                             ((nn & 63) >> 3) * 512 + d * 8 + (nn & 7);
          *(ushort4*)&vo[off] = o;
        } else if (z == 1) {
#pragma unroll
          for (int i = 0; i < 4; i++) {
            const int R = rb + m * 16 + i;
            const int b = R >> 11, nn = R & 2047;
            const int bh = b * 16 + h;
            const size_t off = (size_t)bh * 131072 + (size_t)(nn >> 6) * 4096 +
                               (d >> 3) * 512 + (nn & 63) * 8 + (d & 7);
            ko[off] = f2bf(acc[m][n][i]);
          }
        } else {
          const float s = 0.03125f * L2E;  // q pre-scale incl log2(e)
#pragma unroll
          for (int i = 0; i < 4; i++) {
            const int R = rb + m * 16 + i;
            const int b = R >> 11, nn = R & 2047;
            qo[(size_t)((b * 16 + h) * 2048 + nn) * 64 + d] = f2bf(acc[m][n][i] * s);
          }
        }
      }
    }
  }
}

// ---------------- flash attention (R6 structure, epilogue -> A_blk) --------
__global__ __launch_bounds__(256, 2) void k_attn(const u16* __restrict__ qg,
                                                 const u16* __restrict__ kg,
                                                 const u16* __restrict__ vg,
                                                 u16* __restrict__ att) {
  __shared__ u16 SM[16384];
  const int tid = threadIdx.x;
  const int lane = tid & 63, wv = tid >> 6;
  const int lo5 = lane & 31, hi = lane >> 5;
  const int bh = blockIdx.y;
  const int b = bh >> 4, h = bh & 15;
  const int q0w = blockIdx.x * 128 + wv * 32;
  const size_t qbase = (size_t)bh * 2048 * 64;
  const u16* kt0 = kg + (size_t)bh * 131072;
  const u16* vt0 = vg + (size_t)bh * 131072;

  bf16x8 qb[4];
  {
    const u16* qp = qg + qbase + (size_t)(q0w + lo5) * 64 + hi * 8;
#pragma unroll
    for (int db = 0; db < 4; db++) qb[db] = *(const bf16x8*)(qp + db * 16);
  }

  f32x16 o0, o1;
#pragma unroll
  for (int i = 0; i < 16; i++) { o0[i] = 0.f; o1[i] = 0.f; }
  float m_run = -3.0e38f;
  float l16[16];
#pragma unroll
  for (int i = 0; i < 16; i++) l16[i] = 0.f;

  gload_lds16(kt0 + (size_t)tid * 8, SM + wv * 512);
  gload_lds16(kt0 + (size_t)(256 + tid) * 8, SM + 2048 + wv * 512);
  gload_lds16(vt0 + (size_t)tid * 8, SM + 4096 + wv * 512);
  gload_lds16(vt0 + (size_t)(256 + tid) * 8, SM + 6144 + wv * 512);
  __syncthreads();

  int cur = 0;
  for (int t = 0; t < 32; t++) {
    {
      const int nt = (t + 1) & 31;
      const u16* ks = kt0 + (size_t)nt * 4096;
      const u16* vs = vt0 + (size_t)nt * 4096;
      u16* Kd = SM + (cur ^ 1) * 8192;
      gload_lds16(ks + (size_t)tid * 8, Kd + wv * 512);
      gload_lds16(ks + (size_t)(256 + tid) * 8, Kd + 2048 + wv * 512);
      gload_lds16(vs + (size_t)tid * 8, Kd + 4096 + wv * 512);
      gload_lds16(vs + (size_t)(256 + tid) * 8, Kd + 6144 + wv * 512);
    }

    const u16* Kc = SM + cur * 8192 + hi * 512 + lo5 * 8;
    const u16* Vc = Kc + 4096;

    f32x16 s0, s1;
#pragma unroll
    for (int i = 0; i < 16; i++) { s0[i] = 0.f; s1[i] = 0.f; }
    __builtin_amdgcn_s_setprio(1);
#pragma unroll
    for (int db = 0; db < 4; db++) {
      const bf16x8 k0 = *(const bf16x8*)&Kc[db * 1024];
      const bf16x8 k1 = *(const bf16x8*)&Kc[db * 1024 + 256];
      s0 = __builtin_amdgcn_mfma_f32_32x32x16_bf16(k0, qb[db], s0, 0, 0, 0);
      s1 = __builtin_amdgcn_mfma_f32_32x32x16_bf16(k1, qb[db], s1, 0, 0, 0);
    }
    __builtin_amdgcn_s_setprio(0);

    float tmx[16];
#pragma unroll
    for (int i = 0; i < 16; i++) tmx[i] = fmaxf(s0[i], s1[i]);
#pragma unroll
    for (int off = 8; off; off >>= 1)
#pragma unroll
      for (int i = 0; i < off; i++) tmx[i] = fmaxf(tmx[i], tmx[i + off]);
    const float tmax = fmaxf(tmx[0], __shfl_xor(tmx[0], 32, 64));

    const bool skip = __all(tmax - m_run <= 8.0f);
    if (!skip) {
      const float mnew = fmaxf(m_run, tmax);
      const float sc = __builtin_amdgcn_exp2f(m_run - mnew);
      m_run = mnew;
#pragma unroll
      for (int i = 0; i < 16; i++) { l16[i] *= sc; o0[i] *= sc; o1[i] *= sc; }
    }

    float p0[16], p1[16];
#pragma unroll
    for (int i = 0; i < 16; i++) {
      p0[i] = __builtin_amdgcn_exp2f(s0[i] - m_run);
      p1[i] = __builtin_amdgcn_exp2f(s1[i] - m_run);
      l16[i] += p0[i] + p1[i];
    }

    bf16x8 pa[4];
#pragma unroll
    for (int kh = 0; kh < 2; kh++) {
      const float* pp = kh ? p1 : p0;
#pragma unroll
      for (int kl = 0; kl < 2; kl++) {
        const int r0 = kl * 8;
        const u32 a0 = cvtpk(pp[r0 + 0], pp[r0 + 1]);
        const u32 a1 = cvtpk(pp[r0 + 2], pp[r0 + 3]);
        const u32 b0 = cvtpk(pp[r0 + 4], pp[r0 + 5]);
        const u32 b1 = cvtpk(pp[r0 + 6], pp[r0 + 7]);
        const u32 a0x = (u32)__shfl_xor((int)a0, 32, 64);
        const u32 a1x = (u32)__shfl_xor((int)a1, 32, 64);
        const u32 b0x = (u32)__shfl_xor((int)b0, 32, 64);
        const u32 b1x = (u32)__shfl_xor((int)b1, 32, 64);
        union { u32 w[4]; bf16x8 v; } U;
        U.w[0] = hi ? b0x : a0;
        U.w[1] = hi ? b1x : a1;
        U.w[2] = hi ? b0 : a0x;
        U.w[3] = hi ? b1 : a1x;
        pa[kh * 2 + kl] = U.v;
      }
    }

    __builtin_amdgcn_s_setprio(1);
#pragma unroll
    for (int ks = 0; ks < 4; ks++) {
      const bf16x8 v0 = *(const bf16x8*)&Vc[ks * 1024];
      const bf16x8 v1 = *(const bf16x8*)&Vc[ks * 1024 + 256];
      o0 = __builtin_amdgcn_mfma_f32_32x32x16_bf16(v0, pa[ks], o0, 0, 0, 0);
      o1 = __builtin_amdgcn_mfma_f32_32x32x16_bf16(v1, pa[ks], o1, 0, 0, 0);
    }
    __builtin_amdgcn_s_setprio(0);

    __syncthreads();
    cur ^= 1;
  }

  float ls[8];
#pragma unroll
  for (int i = 0; i < 8; i++) ls[i] = l16[i] + l16[i + 8];
#pragma unroll
  for (int off = 4; off; off >>= 1)
#pragma unroll
    for (int i = 0; i < off; i++) ls[i] += ls[i + off];
  const float lsum = ls[0] + __shfl_xor(ls[0], 32, 64);
  const float linv = 1.0f / lsum;

  u16* W = SM + wv * 2176;
#pragma unroll
  for (int r = 0; r < 16; r++) {
    const int dd = (r & 3) + 8 * (r >> 2) + 4 * hi;
    W[lo5 * 68 + dd] = f2bf(o0[r] * linv);
    W[lo5 * 68 + 32 + dd] = f2bf(o1[r] * linv);
  }
  // store O rows into A_blk layout (consumed by k_mm<1>)
  const int q_loc = lane >> 1, dh = (lane & 1) * 32;
  const int nrow = b * 2048 + q0w + q_loc;
  const size_t rowpart = (size_t)(nrow >> 7) * 4096 + (nrow & 127) * 8;
#pragma unroll
  for (int c = 0; c < 4; c++) {
    const int kk = h * 64 + dh + c * 8;
    bf16x8 val = *(const bf16x8*)&W[q_loc * 68 + dh + c * 8];
    const size_t off = (size_t)(kk >> 5) * 262144 + rowpart + ((kk >> 3) & 3) * 1024;
    *(bf16x8*)(att + off) = val;
  }
}

extern "C" void kernel_launch(void* const* d_in, const int* in_sizes, int n_in,
                              void* d_out, int out_size, void* d_ws, size_t ws_size,
                              hipStream_t stream) {
  const float* x  = (const float*)d_in[0];
  const float* Wq = (const float*)d_in[1];
  const float* Wk = (const float*)d_in[2];
  const float* Wv = (const float*)d_in[3];
  const float* Wo = (const float*)d_in[4];
  float* out = (float*)d_out;

  char* ws = (char*)d_ws;
  u16* xb   = (u16*)ws; ws += (size_t)8192 * 1024 * 2;   // A_blk
  u16* wqkv = (u16*)ws; ws += (size_t)3072 * 1024 * 2;   // B_blk concat
  u16* woT  = (u16*)ws; ws += (size_t)1024 * 1024 * 2;   // B_blk
  u16* qb   = (u16*)ws; ws += (size_t)8192 * 1024 * 2;
  u16* kb   = (u16*)ws; ws += (size_t)8192 * 1024 * 2;
  u16* vb   = (u16*)ws; ws += (size_t)8192 * 1024 * 2;
  u16* att  = (u16*)ws; ws += (size_t)8192 * 1024 * 2;   // A_blk

  k_cvt<<<dim3(8192), dim3(256), 0, stream>>>(x, xb);
  k_tw<<<dim3(16, 16, 4), dim3(256), 0, stream>>>(Wq, Wk, Wv, Wo, wqkv, woT);
  k_mm<0><<<dim3(12, 64), dim3(512), 0, stream>>>(xb, wqkv, qb, kb, vb, nullptr);
  k_attn<<<dim3(16, 64), dim3(256), 0, stream>>>(qb, kb, vb, att);
  k_mm<1><<<dim3(4, 64), dim3(512), 0, stream>>>(att, woT, nullptr, nullptr, nullptr, out);
}